// Round 13
// baseline (234.754 us; speedup 1.0000x reference)
//
#include <hip/hip_runtime.h>
#include <math.h>

#define SEQL 4096
#define L2E 1.44269504088896340736f

#if defined(__has_builtin)
#if __has_builtin(__builtin_amdgcn_exp2f)
#define FAST_EXP2(x) __builtin_amdgcn_exp2f(x)
#endif
#endif
#ifndef FAST_EXP2
#define FAST_EXP2(x) exp2f(x)
#endif

__device__ __forceinline__ float sigmoid_f(float x){ return 1.0f/(1.0f+expf(-x)); }

// ---------------- conv 3x3, pad 1, 64x64 image (known-good R9 config) ------
template<int CI, int CO, int COG, bool RELU, bool RES>
__global__ __launch_bounds__(256) void conv3x3_k(const float* __restrict__ in,
    const float* __restrict__ wgt, const float* __restrict__ bias,
    const float* __restrict__ res, float* __restrict__ out)
{
  constexpr int CIT = CI/4;
  __shared__ float tin[4][2][6][72];
  __shared__ float red[3][4][COG][66];
  const int tid  = threadIdx.x;
  const int lane = tid & 63;
  const int ty   = tid >> 6;
  const int h0   = blockIdx.x * 4;
  const int co0  = blockIdx.y * COG;
  const int b    = blockIdx.z;

  if (lane < 24){
    int cl = lane / 12, rem = lane % 12, r = rem >> 1, side = rem & 1;
    tin[ty][cl][r][side ? 68 : 3] = 0.0f;
  }

  float acc[4][COG];
  #pragma unroll
  for (int rr=0;rr<4;++rr)
    #pragma unroll
    for (int u=0;u<COG;++u) acc[rr][u] = 0.0f;

  const int ci0 = ty*CIT;
  for (int cig = ci0; cig < ci0 + CIT; cig += 2){
    #pragma unroll
    for (int k=0;k<3;++k){
      int idx4 = lane + (k<<6);
      int row  = idx4 >> 4;
      int cl = row/6, r = row - cl*6;
      int w4 = (idx4 & 15) << 2;
      int h  = h0 - 1 + r;
      float4 v = make_float4(0.f,0.f,0.f,0.f);
      if (h>=0 && h<64)
        v = *(const float4*)(in + ((size_t)(b*CI+cig+cl)*64 + h)*64 + w4);
      *(float4*)&tin[ty][cl][r][4+w4] = v;
    }
    #pragma unroll
    for (int cl=0; cl<2; ++cl){
      float rv[6][3];
      #pragma unroll
      for (int r=0;r<6;++r)
        #pragma unroll
        for (int c=0;c<3;++c)
          rv[r][c] = tin[ty][cl][r][3+lane+c];
      #pragma unroll
      for (int u=0;u<COG;++u){
        const float* wp = wgt + ((size_t)(co0+u)*CI + cig + cl)*9;
        #pragma unroll
        for (int rr=0;rr<4;++rr)
          #pragma unroll
          for (int j=0;j<3;++j){
            acc[rr][u] = fmaf(rv[rr+j][0], wp[3*j+0], acc[rr][u]);
            acc[rr][u] = fmaf(rv[rr+j][1], wp[3*j+1], acc[rr][u]);
            acc[rr][u] = fmaf(rv[rr+j][2], wp[3*j+2], acc[rr][u]);
          }
      }
    }
  }
  if (ty > 0){
    #pragma unroll
    for (int rr=0;rr<4;++rr)
      #pragma unroll
      for (int u=0;u<COG;++u) red[ty-1][rr][u][lane] = acc[rr][u];
  }
  __syncthreads();
  if (ty == 0){
    #pragma unroll
    for (int rr=0;rr<4;++rr)
      #pragma unroll
      for (int u=0;u<COG;++u){
        float s = acc[rr][u] + red[0][rr][u][lane] + red[1][rr][u][lane]
                + red[2][rr][u][lane] + bias[co0+u];
        size_t ob = ((size_t)(b*CO+co0+u)*64 + h0+rr)*64 + lane;
        if constexpr (RES)  s += res[ob];
        if constexpr (RELU) s = fmaxf(s, 0.0f);
        out[ob] = s;
      }
  }
}

// ---- fused mamba front + scan pass 1, 32-token tiles (512 blocks, 2/CU) ----
__global__ __launch_bounds__(512) void mamba_in_k(const float* __restrict__ x2,
    const float* __restrict__ g, const float* __restrict__ be,
    const float* __restrict__ Wip, const float* __restrict__ cw,
    const float* __restrict__ cb, const float* __restrict__ Wxp,
    const float* __restrict__ Wdt, const float* __restrict__ bdt,
    const float* __restrict__ A_log,
    float* __restrict__ xm2, float* __restrict__ szb, float* __restrict__ dlt,
    float* __restrict__ Bm, float* __restrict__ Cm,
    float* __restrict__ cA, float* __restrict__ cH)
{
  __shared__ float xn[35][37];   // LN'd tokens l0-3 .. l0+31
  __shared__ float xm[64][36];   // in_proj xm half [d][t]; cols 0..31 later = dl[d][tok]
  __shared__ float xt[32][67];   // silu(conv) [tok][d]
  __shared__ float xd[32][67];   // x_dbl [tok][j]
  const int tid = threadIdx.x;
  const int bi = blockIdx.x >> 7;
  const int chunk = blockIdx.x & 127;
  const int l0 = chunk << 5;

  if (tid < 35){
    int tok = l0 - 3 + tid;
    if (tok >= 0){
      const float* row = x2 + (size_t)bi*131072 + (size_t)tok*32;
      float v[32];
      #pragma unroll
      for (int c=0;c<32;c+=4){
        float4 f = *(const float4*)(row + c);
        v[c]=f.x; v[c+1]=f.y; v[c+2]=f.z; v[c+3]=f.w;
      }
      float p[8];
      #pragma unroll
      for (int j2=0;j2<8;++j2) p[j2]=v[j2];
      #pragma unroll
      for (int i=8;i<32;i+=8){
        #pragma unroll
        for (int j2=0;j2<8;++j2) p[j2]+=v[i+j2];
      }
      float mu = (((p[0]+p[1])+(p[2]+p[3]))+((p[4]+p[5])+(p[6]+p[7]))) * 0.03125f;
      float q[8];
      #pragma unroll
      for (int j2=0;j2<8;++j2){ float dd=v[j2]-mu; q[j2]=dd*dd; }
      #pragma unroll
      for (int i=8;i<32;i+=8){
        #pragma unroll
        for (int j2=0;j2<8;++j2){ float dd=v[i+j2]-mu; q[j2]+=dd*dd; }
      }
      float var = (((q[0]+q[1])+(q[2]+q[3]))+((q[4]+q[5])+(q[6]+q[7]))) * 0.03125f;
      float rstd = 1.0f / sqrtf(var + 1e-5f);
      #pragma unroll
      for (int c=0;c<32;++c) xn[tid][c] = (v[c]-mu)*rstd*g[c] + be[c];
    } else {
      #pragma unroll
      for (int c=0;c<32;++c) xn[tid][c] = 0.0f;
    }
  }
  __syncthreads();

  // in_proj main: 32 tokens x 128 j
  {
    const int t = tid & 31, jg = tid >> 5;    // jg 0..15
    float xv[32];
    #pragma unroll
    for (int c=0;c<32;++c) xv[c] = xn[t+3][c];
    #pragma unroll
    for (int k=0;k<8;++k){
      int j = jg*8 + k;
      const float* wr = Wip + j*32;
      float a = 0.0f;
      #pragma unroll
      for (int c=0;c<32;++c) a = fmaf(xv[c], wr[c], a);
      if (j < 64) xm[j][t+3] = a;
      else        szb[((size_t)(bi*64 + (j-64)))*SEQL + l0 + t] = a * sigmoid_f(a);
    }
  }
  // in_proj halo: tokens 0..2, xm half only
  if (tid < 192){
    int t = tid % 3, j = tid / 3;             // j 0..63
    float xv[32];
    #pragma unroll
    for (int c=0;c<32;++c) xv[c] = xn[t][c];
    const float* wr = Wip + j*32;
    float a = 0.0f;
    #pragma unroll
    for (int c=0;c<32;++c) a = fmaf(xv[c], wr[c], a);
    xm[j][t] = a;
  }
  __syncthreads();

  // depthwise conv1d k=4 + silu
  {
    const int d = tid >> 3, t0 = (tid & 7) << 2;
    const float w0=cw[d*4], w1=cw[d*4+1], w2=cw[d*4+2], w3=cw[d*4+3], bv=cb[d];
    float r[4];
    #pragma unroll
    for (int k=0;k<4;++k){
      int t = t0 + k;
      float a = xm[d][t]*w0 + xm[d][t+1]*w1 + xm[d][t+2]*w2 + xm[d][t+3]*w3 + bv;
      float s = a * sigmoid_f(a);
      xt[t][d] = s;
      r[k] = s;
    }
    *(float4*)(xm2 + ((size_t)(bi*64+d))*SEQL + l0 + t0) = make_float4(r[0],r[1],r[2],r[3]);
  }
  __syncthreads();

  // x_proj 64->66
  {
    const int tok = tid & 31, jg = tid >> 5;
    float xv[64];
    #pragma unroll
    for (int c=0;c<64;++c) xv[c] = xt[tok][c];
    for (int j=jg; j<66; j+=16){
      const float* wr = Wxp + j*64;
      float a = 0.0f;
      #pragma unroll
      for (int c=0;c<64;++c) a = fmaf(xv[c], wr[c], a);
      xd[tok][j] = a;
    }
  }
  __syncthreads();

  // dt_proj + softplus (dl -> xm alias), B/C split
  {
    const int tok = tid & 31, gg = tid >> 5;
    float dt0 = xd[tok][0], dt1 = xd[tok][1];
    #pragma unroll
    for (int k=0;k<4;++k){
      int d2 = gg*4 + k;
      float v = dt0*Wdt[d2*2] + dt1*Wdt[d2*2+1] + bdt[d2];
      float sp = fmaxf(v,0.0f) + log1pf(expf(-fabsf(v)));
      dlt[((size_t)(bi*64+d2))*SEQL + l0 + tok] = sp;
      xm[d2][tok] = sp;
    }
    const int which = gg >> 3, n0 = (gg & 7)*4;
    float* dst = which ? Cm : Bm;
    const int s0 = 2 + which*32 + n0;
    float4 f;
    f.x = xd[tok][s0]; f.y = xd[tok][s0+1]; f.z = xd[tok][s0+2]; f.w = xd[tok][s0+3];
    *(float4*)(dst + ((size_t)bi*SEQL + l0 + tok)*32 + n0) = f;
  }
  __syncthreads();

  // scan pass 1 (fused): per-chunk (prod a, h_end), 64 d x 32 n
  {
    const int d  = tid >> 3;
    const int gg = tid & 7;
    const int bd = bi*64 + d;
    float Av2[4], h[4] = {0,0,0,0}, aP[4] = {1,1,1,1};
    #pragma unroll
    for (int j=0;j<4;++j) Av2[j] = -expf(A_log[d*32 + gg + 8*j]) * L2E;
    #pragma unroll 4
    for (int t=0;t<32;++t){
      float dlv = xm[d][t];
      float xv2 = xt[t][d];
      #pragma unroll
      for (int j=0;j<4;++j){
        float bv = xd[t][2 + gg + 8*j];
        float a = FAST_EXP2(dlv*Av2[j]);
        h[j] = fmaf(a, h[j], dlv*bv*xv2);
        aP[j] *= a;
      }
    }
    #pragma unroll
    for (int j=0;j<4;++j){
      size_t idx = (((size_t)bd<<5) + gg + 8*j)*128 + chunk;
      cA[idx] = aP[j]; cH[idx] = h[j];
    }
  }
}

// ---- scan pass 2, chunk=32, inline prefix. 4096 blocks (16/CU). ----
__global__ __launch_bounds__(256) void scan_p2(const float* __restrict__ dlt,
    const float* __restrict__ xssm, const float* __restrict__ Bm,
    const float* __restrict__ Cm, const float* __restrict__ A_log,
    const float* __restrict__ Dp, const float* __restrict__ sz,
    const float* __restrict__ cA, const float* __restrict__ cHs,
    float* __restrict__ yt)
{
  __shared__ float pre[32][9];
  const int tid = threadIdx.x;
  const int n = tid & 31;
  const int grp = blockIdx.x & 15;
  const int chunk = grp*8 + (tid >> 5);
  const int bd = blockIdx.x >> 4;
  const int b = bd >> 6, d = bd & 63;
  const int l0 = chunk << 5;

  if (tid < 32){
    const float* pa = cA  + (((size_t)bd<<5)+tid)*128;
    const float* ph = cHs + (((size_t)bd<<5)+tid)*128;
    float hrun = 0.0f;
    for (int c=0;c<grp*8;c+=4){
      float4 a4 = *(const float4*)(pa+c);
      float4 h4 = *(const float4*)(ph+c);
      hrun = fmaf(a4.x,hrun,h4.x);
      hrun = fmaf(a4.y,hrun,h4.y);
      hrun = fmaf(a4.z,hrun,h4.z);
      hrun = fmaf(a4.w,hrun,h4.w);
    }
    int c = grp*8;
    float4 a4 = *(const float4*)(pa+c);
    float4 h4 = *(const float4*)(ph+c);
    pre[tid][0]=hrun; hrun=fmaf(a4.x,hrun,h4.x);
    pre[tid][1]=hrun; hrun=fmaf(a4.y,hrun,h4.y);
    pre[tid][2]=hrun; hrun=fmaf(a4.z,hrun,h4.z);
    pre[tid][3]=hrun; hrun=fmaf(a4.w,hrun,h4.w);
    a4 = *(const float4*)(pa+c+4);
    h4 = *(const float4*)(ph+c+4);
    pre[tid][4]=hrun; hrun=fmaf(a4.x,hrun,h4.x);
    pre[tid][5]=hrun; hrun=fmaf(a4.y,hrun,h4.y);
    pre[tid][6]=hrun; hrun=fmaf(a4.z,hrun,h4.z);
    pre[tid][7]=hrun;
  }
  __syncthreads();

  const float Av2 = -expf(A_log[d*32+n]) * L2E;
  const float Dv = Dp[d];
  const float* del = dlt  + (size_t)bd*SEQL + l0;
  const float* xp  = xssm + (size_t)bd*SEQL + l0;
  const float* szp = sz   + (size_t)bd*SEQL + l0;
  const float* Bp  = Bm + ((size_t)b*SEQL + l0)*32 + n;
  const float* Cp  = Cm + ((size_t)b*SEQL + l0)*32 + n;
  float* yp = yt + (size_t)bd*SEQL + l0;
  float h = pre[n][tid >> 5];
  #pragma unroll 2
  for (int i0=0;i0<32;i0+=4){
    float4 d4 = *(const float4*)(del+i0);
    float4 x4 = *(const float4*)(xp +i0);
    float4 s4 = *(const float4*)(szp+i0);
    float b0 = Bp[(i0+0)*32], b1 = Bp[(i0+1)*32], b2 = Bp[(i0+2)*32], b3 = Bp[(i0+3)*32];
    float c0 = Cp[(i0+0)*32], c1 = Cp[(i0+1)*32], c2 = Cp[(i0+2)*32], c3 = Cp[(i0+3)*32];
    float a0 = FAST_EXP2(d4.x*Av2); h = fmaf(a0,h, d4.x*b0*x4.x);
    float v0 = h*c0;
    float a1 = FAST_EXP2(d4.y*Av2); h = fmaf(a1,h, d4.y*b1*x4.y);
    float v1 = h*c1;
    float a2 = FAST_EXP2(d4.z*Av2); h = fmaf(a2,h, d4.z*b2*x4.z);
    float v2 = h*c2;
    float a3 = FAST_EXP2(d4.w*Av2); h = fmaf(a3,h, d4.w*b3*x4.w);
    float v3 = h*c3;
    v0 += __shfl_xor(v0,16); v0 += __shfl_xor(v0,8); v0 += __shfl_xor(v0,4);
    v0 += __shfl_xor(v0,2);  v0 += __shfl_xor(v0,1);
    v1 += __shfl_xor(v1,16); v1 += __shfl_xor(v1,8); v1 += __shfl_xor(v1,4);
    v1 += __shfl_xor(v1,2);  v1 += __shfl_xor(v1,1);
    v2 += __shfl_xor(v2,16); v2 += __shfl_xor(v2,8); v2 += __shfl_xor(v2,4);
    v2 += __shfl_xor(v2,2);  v2 += __shfl_xor(v2,1);
    v3 += __shfl_xor(v3,16); v3 += __shfl_xor(v3,8); v3 += __shfl_xor(v3,4);
    v3 += __shfl_xor(v3,2);  v3 += __shfl_xor(v3,1);
    if (n==0){
      yp[i0+0] = fmaf(x4.x, Dv, v0) * s4.x;
      yp[i0+1] = fmaf(x4.y, Dv, v1) * s4.y;
      yp[i0+2] = fmaf(x4.z, Dv, v2) * s4.z;
      yp[i0+3] = fmaf(x4.w, Dv, v3) * s4.w;
    }
  }
}

// ---------------- out_proj (64->32) into (b,c,l) = NCHW image --------------
__global__ __launch_bounds__(512) void outproj_k(const float* __restrict__ yt,
    const float* __restrict__ Wout, float* __restrict__ ym)
{
  __shared__ float ys[64][67];
  const int tid = threadIdx.x, lane = tid & 63, ty = tid >> 6;
  const int bi = blockIdx.x >> 6;
  const int l0 = (blockIdx.x & 63) << 6;
  for (int r=ty; r<64; r+=8)
    ys[lane][r] = yt[((size_t)(bi*64+r))*SEQL + l0 + lane];
  __syncthreads();
  float yv[64];
  #pragma unroll
  for (int c=0;c<64;++c) yv[c] = ys[lane][c];
  #pragma unroll
  for (int jj=0;jj<4;++jj){
    int j = ty*4 + jj;
    const float* wr = Wout + j*64;
    float acc = 0.0f;
    #pragma unroll
    for (int c=0;c<64;++c) acc = fmaf(yv[c], wr[c], acc);
    ym[((size_t)(bi*32+j))*SEQL + l0 + lane] = acc;
  }
}

extern "C" void kernel_launch(void* const* d_in, const int* in_sizes, int n_in,
                              void* d_out, int out_size, void* d_ws, size_t ws_size,
                              hipStream_t stream) {
  const float* x        = (const float*)d_in[0];
  const float* conv1_w  = (const float*)d_in[1];
  const float* conv1_b  = (const float*)d_in[2];
  const float* conv2_w  = (const float*)d_in[3];
  const float* conv2_b  = (const float*)d_in[4];
  const float* ln_g     = (const float*)d_in[5];
  const float* ln_b     = (const float*)d_in[6];
  const float* in_proj_w= (const float*)d_in[7];
  const float* conv1d_w = (const float*)d_in[8];
  const float* conv1d_b = (const float*)d_in[9];
  const float* x_proj_w = (const float*)d_in[10];
  const float* dt_proj_w= (const float*)d_in[11];
  const float* dt_proj_b= (const float*)d_in[12];
  const float* A_log    = (const float*)d_in[13];
  const float* Dp       = (const float*)d_in[14];
  const float* out_proj_w=(const float*)d_in[15];
  const float* smooth_w = (const float*)d_in[16];
  const float* smooth_b = (const float*)d_in[17];
  float* out = (float*)d_out;

  float* ws = (float*)d_ws;
  float* t      = ws;                 // (4,64,64,64)  1048576
  float* x2     = t      + 1048576;   // (4,32,4096)    524288
  float* xm2    = x2     + 524288;    // (4,64,4096)   1048576
  float* szb    = xm2    + 1048576;   // (4,64,4096)   1048576
  float* dlt    = szb    + 1048576;   // (4,64,4096)   1048576
  float* Bmat   = dlt    + 1048576;   // (4,4096,32)    524288
  float* Cmat   = Bmat   + 524288;    // (4,4096,32)    524288
  float* yt     = Cmat   + 524288;    // (4,64,4096)   1048576
  float* ym     = yt     + 1048576;   // (4,32,4096)    524288
  float* cA     = ym     + 524288;    // (256,32,128)  1048576
  float* cH     = cA     + 1048576;   // (256,32,128)  1048576

  conv3x3_k<32,64,4,true ,false><<<dim3(16,16,4), 256, 0, stream>>>(x,  conv1_w, conv1_b, nullptr, t);
  conv3x3_k<64,32,4,false,true ><<<dim3(16,8,4), 256, 0, stream>>>(t,  conv2_w, conv2_b, x,       x2);
  mamba_in_k  <<<512, 512, 0, stream>>>(x2, ln_g, ln_b, in_proj_w, conv1d_w, conv1d_b,
                                        x_proj_w, dt_proj_w, dt_proj_b, A_log,
                                        xm2, szb, dlt, Bmat, Cmat, cA, cH);
  scan_p2     <<<4096, 256, 0, stream>>>(dlt, xm2, Bmat, Cmat, A_log, Dp, szb, cA, cH, yt);
  outproj_k   <<<256, 512, 0, stream>>>(yt, out_proj_w, ym);
  conv3x3_k<32,32,4,false,false><<<dim3(16,8,4), 256, 0, stream>>>(ym, smooth_w, smooth_b, nullptr, out);
}

// Round 14
// 205.155 us; speedup vs baseline: 1.1443x; 1.1443x over previous
//
#include <hip/hip_runtime.h>
#include <math.h>

#define SEQL 4096
#define L2E 1.44269504088896340736f

#if defined(__has_builtin)
#if __has_builtin(__builtin_amdgcn_exp2f)
#define FAST_EXP2(x) __builtin_amdgcn_exp2f(x)
#endif
#endif
#ifndef FAST_EXP2
#define FAST_EXP2(x) exp2f(x)
#endif

__device__ __forceinline__ float sigmoid_f(float x){ return 1.0f/(1.0f+expf(-x)); }

// ---------------- conv 3x3, pad 1, 64x64 image (known-good R9 config) ------
template<int CI, int CO, int COG, bool RELU, bool RES>
__global__ __launch_bounds__(256) void conv3x3_k(const float* __restrict__ in,
    const float* __restrict__ wgt, const float* __restrict__ bias,
    const float* __restrict__ res, float* __restrict__ out)
{
  constexpr int CIT = CI/4;
  __shared__ float tin[4][2][6][72];
  __shared__ float red[3][4][COG][66];
  const int tid  = threadIdx.x;
  const int lane = tid & 63;
  const int ty   = tid >> 6;
  const int h0   = blockIdx.x * 4;
  const int co0  = blockIdx.y * COG;
  const int b    = blockIdx.z;

  if (lane < 24){
    int cl = lane / 12, rem = lane % 12, r = rem >> 1, side = rem & 1;
    tin[ty][cl][r][side ? 68 : 3] = 0.0f;
  }

  float acc[4][COG];
  #pragma unroll
  for (int rr=0;rr<4;++rr)
    #pragma unroll
    for (int u=0;u<COG;++u) acc[rr][u] = 0.0f;

  const int ci0 = ty*CIT;
  for (int cig = ci0; cig < ci0 + CIT; cig += 2){
    #pragma unroll
    for (int k=0;k<3;++k){
      int idx4 = lane + (k<<6);
      int row  = idx4 >> 4;
      int cl = row/6, r = row - cl*6;
      int w4 = (idx4 & 15) << 2;
      int h  = h0 - 1 + r;
      float4 v = make_float4(0.f,0.f,0.f,0.f);
      if (h>=0 && h<64)
        v = *(const float4*)(in + ((size_t)(b*CI+cig+cl)*64 + h)*64 + w4);
      *(float4*)&tin[ty][cl][r][4+w4] = v;
    }
    #pragma unroll
    for (int cl=0; cl<2; ++cl){
      float rv[6][3];
      #pragma unroll
      for (int r=0;r<6;++r)
        #pragma unroll
        for (int c=0;c<3;++c)
          rv[r][c] = tin[ty][cl][r][3+lane+c];
      #pragma unroll
      for (int u=0;u<COG;++u){
        const float* wp = wgt + ((size_t)(co0+u)*CI + cig + cl)*9;
        #pragma unroll
        for (int rr=0;rr<4;++rr)
          #pragma unroll
          for (int j=0;j<3;++j){
            acc[rr][u] = fmaf(rv[rr+j][0], wp[3*j+0], acc[rr][u]);
            acc[rr][u] = fmaf(rv[rr+j][1], wp[3*j+1], acc[rr][u]);
            acc[rr][u] = fmaf(rv[rr+j][2], wp[3*j+2], acc[rr][u]);
          }
      }
    }
  }
  if (ty > 0){
    #pragma unroll
    for (int rr=0;rr<4;++rr)
      #pragma unroll
      for (int u=0;u<COG;++u) red[ty-1][rr][u][lane] = acc[rr][u];
  }
  __syncthreads();
  if (ty == 0){
    #pragma unroll
    for (int rr=0;rr<4;++rr)
      #pragma unroll
      for (int u=0;u<COG;++u){
        float s = acc[rr][u] + red[0][rr][u][lane] + red[1][rr][u][lane]
                + red[2][rr][u][lane] + bias[co0+u];
        size_t ob = ((size_t)(b*CO+co0+u)*64 + h0+rr)*64 + lane;
        if constexpr (RES)  s += res[ob];
        if constexpr (RELU) s = fmaxf(s, 0.0f);
        out[ob] = s;
      }
  }
}

// ---- fused mamba front + scan pass 1 (R12 structure, 64-token tiles).
//      B/C stored PERMUTED: position q*4+j holds n=q+8j (float4 per lane in p2).
__global__ __launch_bounds__(512) void mamba_in_k(const float* __restrict__ x2,
    const float* __restrict__ g, const float* __restrict__ be,
    const float* __restrict__ Wip, const float* __restrict__ cw,
    const float* __restrict__ cb, const float* __restrict__ Wxp,
    const float* __restrict__ Wdt, const float* __restrict__ bdt,
    const float* __restrict__ A_log,
    float* __restrict__ xm2, float* __restrict__ szb, float* __restrict__ dlt,
    float* __restrict__ Bm, float* __restrict__ Cm,
    float* __restrict__ cA, float* __restrict__ cH)
{
  __shared__ float xn[68][37];   // LN'd tokens (stride 37)
  __shared__ float xm[64][68];   // in_proj xm half [d][t]; later aliased as dl[d][tok]
  __shared__ float xt[64][67];   // silu(conv) [tok][d]
  __shared__ float xd[64][67];   // x_dbl [tok][j]
  const int tid = threadIdx.x, lane = tid & 63, ty = tid >> 6;  // ty 0..7
  const int bi = blockIdx.x >> 6;
  const int l0 = (blockIdx.x & 63) << 6;

  if (ty < 2){
    int t = ty*64 + lane;
    if (t < 67){
      int tok = l0 - 3 + t;
      if (tok >= 0){
        const float* row = x2 + (size_t)bi*131072 + (size_t)tok*32;
        float v[32];
        #pragma unroll
        for (int c=0;c<32;c+=4){
          float4 f = *(const float4*)(row + c);
          v[c]=f.x; v[c+1]=f.y; v[c+2]=f.z; v[c+3]=f.w;
        }
        float p[8];
        #pragma unroll
        for (int j2=0;j2<8;++j2) p[j2]=v[j2];
        #pragma unroll
        for (int i=8;i<32;i+=8){
          #pragma unroll
          for (int j2=0;j2<8;++j2) p[j2]+=v[i+j2];
        }
        float mu = (((p[0]+p[1])+(p[2]+p[3]))+((p[4]+p[5])+(p[6]+p[7]))) * 0.03125f;
        float q[8];
        #pragma unroll
        for (int j2=0;j2<8;++j2){ float dd=v[j2]-mu; q[j2]=dd*dd; }
        #pragma unroll
        for (int i=8;i<32;i+=8){
          #pragma unroll
          for (int j2=0;j2<8;++j2){ float dd=v[i+j2]-mu; q[j2]+=dd*dd; }
        }
        float var = (((q[0]+q[1])+(q[2]+q[3]))+((q[4]+q[5])+(q[6]+q[7]))) * 0.03125f;
        float rstd = 1.0f / sqrtf(var + 1e-5f);
        #pragma unroll
        for (int c=0;c<32;++c) xn[t][c] = (v[c]-mu)*rstd*g[c] + be[c];
      } else {
        #pragma unroll
        for (int c=0;c<32;++c) xn[t][c] = 0.0f;
      }
    }
  }
  __syncthreads();

  const int d0 = ty*8;
  {
    float xvA[32];
    #pragma unroll
    for (int c=0;c<32;++c) xvA[c] = xn[lane][c];
    #pragma unroll
    for (int jj=0;jj<8;++jj){
      const float* wr = Wip + (d0+jj)*32;
      float a = 0.0f;
      #pragma unroll
      for (int c=0;c<32;++c) a = fmaf(xvA[c], wr[c], a);
      xm[d0+jj][lane] = a;
    }
  }
  if (lane < 3){
    float xvB[32];
    #pragma unroll
    for (int c=0;c<32;++c) xvB[c] = xn[64+lane][c];
    #pragma unroll
    for (int jj=0;jj<8;++jj){
      const float* wr = Wip + (d0+jj)*32;
      float a = 0.0f;
      #pragma unroll
      for (int c=0;c<32;++c) a = fmaf(xvB[c], wr[c], a);
      xm[d0+jj][64+lane] = a;
    }
  }
  {
    float xvC[32];
    #pragma unroll
    for (int c=0;c<32;++c) xvC[c] = xn[lane+3][c];
    #pragma unroll
    for (int jj=0;jj<8;++jj){
      const float* wr = Wip + (64+d0+jj)*32;
      float a = 0.0f;
      #pragma unroll
      for (int c=0;c<32;++c) a = fmaf(xvC[c], wr[c], a);
      szb[((size_t)(bi*64+d0+jj))*SEQL + l0 + lane] = a * sigmoid_f(a);
    }
  }
  __syncthreads();

  #pragma unroll
  for (int jj=0;jj<8;++jj){
    int d = d0 + jj;
    float a = xm[d][lane]*cw[d*4] + xm[d][lane+1]*cw[d*4+1]
            + xm[d][lane+2]*cw[d*4+2] + xm[d][lane+3]*cw[d*4+3] + cb[d];
    float s = a * sigmoid_f(a);
    xt[lane][d] = s;
    xm2[((size_t)(bi*64+d))*SEQL + l0 + lane] = s;
  }
  __syncthreads();

  {
    float xv[64];
    #pragma unroll
    for (int c=0;c<64;++c) xv[c] = xt[lane][c];
    for (int j=ty; j<66; j+=8){
      const float* wr = Wxp + j*64;
      float a = 0.0f;
      #pragma unroll
      for (int c=0;c<64;++c) a = fmaf(xv[c], wr[c], a);
      xd[lane][j] = a;
    }
  }
  __syncthreads();

  {
    float dt0 = xd[lane][0], dt1 = xd[lane][1];
    #pragma unroll
    for (int k=0;k<8;++k){
      int d2 = ty*8 + k;
      float v = dt0*Wdt[d2*2] + dt1*Wdt[d2*2+1] + bdt[d2];
      float sp = fmaxf(v,0.0f) + log1pf(expf(-fabsf(v)));
      dlt[((size_t)(bi*64+d2))*SEQL + l0 + lane] = sp;
      xm[d2][lane] = sp;                      // dl[d][tok] (aliases xm)
    }
    // B/C split, PERMUTED: pos q*4+j <- n = q+8j. Thread gq writes q=2gq,2gq+1.
    const int which = ty >> 2, gq = ty & 3;
    float* dst = which ? Cm : Bm;
    size_t base = ((size_t)bi*SEQL + l0 + lane)*32 + gq*8;
    const int s2 = 2 + which*32;
    const int q0 = gq*2;
    float4 f0, f1;
    f0.x = xd[lane][s2+q0+ 0]; f0.y = xd[lane][s2+q0+ 8];
    f0.z = xd[lane][s2+q0+16]; f0.w = xd[lane][s2+q0+24];
    f1.x = xd[lane][s2+q0+ 1]; f1.y = xd[lane][s2+q0+ 9];
    f1.z = xd[lane][s2+q0+17]; f1.w = xd[lane][s2+q0+25];
    *(float4*)(dst + base)     = f0;
    *(float4*)(dst + base + 4) = f1;
  }
  __syncthreads();

  // scan pass 1 (fused): per-chunk (prod a, h_end), chains n = gg+8j
  {
    const int d  = tid >> 3;
    const int gg = tid & 7;
    const int chunk = blockIdx.x & 63;
    const int bd = bi*64 + d;
    float Av2[4], h[4] = {0,0,0,0}, aP[4] = {1,1,1,1};
    #pragma unroll
    for (int j=0;j<4;++j) Av2[j] = -expf(A_log[d*32 + gg + 8*j]) * L2E;
    #pragma unroll 4
    for (int t=0;t<64;++t){
      float dlv = xm[d][t];
      float xv2 = xt[t][d];
      #pragma unroll
      for (int j=0;j<4;++j){
        float bv = xd[t][2 + gg + 8*j];
        float a = FAST_EXP2(dlv*Av2[j]);
        h[j] = fmaf(a, h[j], dlv*bv*xv2);
        aP[j] *= a;
      }
    }
    #pragma unroll
    for (int j=0;j<4;++j){
      size_t idx = (((size_t)bd<<5) + gg + 8*j)*64 + chunk;
      cA[idx] = aP[j]; cH[idx] = h[j];
    }
  }
}

// ---- scan pass 2: 8 lanes/chunk x 4 n-chains/lane (radix-8 reduction,
//      3 shfl/token). Inline prefix (32 threads, chains contiguous).
__global__ __launch_bounds__(256) void scan_p2(const float* __restrict__ dlt,
    const float* __restrict__ xssm, const float* __restrict__ Bm,
    const float* __restrict__ Cm, const float* __restrict__ A_log,
    const float* __restrict__ Dp, const float* __restrict__ sz,
    const float* __restrict__ cA, const float* __restrict__ cHs,
    float* __restrict__ yt)
{
  __shared__ float pre[32][34];
  const int tid = threadIdx.x;
  const int grp = blockIdx.x & 1;            // half: chunks grp*32 .. +31
  const int bd  = blockIdx.x >> 1;
  const int b = bd >> 6, d = bd & 63;
  const int c0 = grp << 5;

  if (tid < 32){
    const float* pa = cA  + (((size_t)bd<<5)+tid)*64;
    const float* ph = cHs + (((size_t)bd<<5)+tid)*64;
    float hrun = 0.0f;
    if (grp){
      #pragma unroll 4
      for (int c=0;c<32;c+=4){
        float4 a4 = *(const float4*)(pa+c);
        float4 h4 = *(const float4*)(ph+c);
        hrun = fmaf(a4.x,hrun,h4.x);
        hrun = fmaf(a4.y,hrun,h4.y);
        hrun = fmaf(a4.z,hrun,h4.z);
        hrun = fmaf(a4.w,hrun,h4.w);
      }
    }
    #pragma unroll 4
    for (int k=0;k<32;k+=4){
      float4 a4 = *(const float4*)(pa+c0+k);
      float4 h4 = *(const float4*)(ph+c0+k);
      pre[tid][k+0]=hrun; hrun=fmaf(a4.x,hrun,h4.x);
      pre[tid][k+1]=hrun; hrun=fmaf(a4.y,hrun,h4.y);
      pre[tid][k+2]=hrun; hrun=fmaf(a4.z,hrun,h4.z);
      pre[tid][k+3]=hrun; hrun=fmaf(a4.w,hrun,h4.w);
    }
  }
  __syncthreads();

  const int lc = tid >> 3, gg = tid & 7;
  const int chunk = c0 + lc;
  const int l0 = chunk << 6;
  const float Dv = Dp[d];
  float Av2[4], h[4];
  #pragma unroll
  for (int j=0;j<4;++j){
    Av2[j] = -expf(A_log[d*32 + gg + 8*j]) * L2E;
    h[j] = pre[gg + 8*j][lc];
  }
  const float* del = dlt  + (size_t)bd*SEQL + l0;
  const float* xp  = xssm + (size_t)bd*SEQL + l0;
  const float* szp = sz   + (size_t)bd*SEQL + l0;
  const float* Bp  = Bm + ((size_t)b*SEQL + l0)*32 + gg*4;
  const float* Cp  = Cm + ((size_t)b*SEQL + l0)*32 + gg*4;
  float* yp = yt + (size_t)bd*SEQL + l0;

  #pragma unroll 2
  for (int i0=0;i0<64;i0+=4){
    float4 d4 = *(const float4*)(del+i0);
    float4 x4 = *(const float4*)(xp +i0);
    float4 s4 = *(const float4*)(szp+i0);
    float y[4];
    #pragma unroll
    for (int t=0;t<4;++t){
      float dl = (t==0)? d4.x : (t==1)? d4.y : (t==2)? d4.z : d4.w;
      float xl = (t==0)? x4.x : (t==1)? x4.y : (t==2)? x4.z : x4.w;
      float sl = (t==0)? s4.x : (t==1)? s4.y : (t==2)? s4.z : s4.w;
      float4 bv = *(const float4*)(Bp + (i0+t)*32);
      float4 cv = *(const float4*)(Cp + (i0+t)*32);
      float a0 = FAST_EXP2(dl*Av2[0]); h[0] = fmaf(a0, h[0], dl*bv.x*xl);
      float a1 = FAST_EXP2(dl*Av2[1]); h[1] = fmaf(a1, h[1], dl*bv.y*xl);
      float a2 = FAST_EXP2(dl*Av2[2]); h[2] = fmaf(a2, h[2], dl*bv.z*xl);
      float a3 = FAST_EXP2(dl*Av2[3]); h[3] = fmaf(a3, h[3], dl*bv.w*xl);
      float v = fmaf(h[3], cv.w, fmaf(h[2], cv.z, fmaf(h[1], cv.y, h[0]*cv.x)));
      v += __shfl_xor(v,1); v += __shfl_xor(v,2); v += __shfl_xor(v,4);
      y[t] = fmaf(xl, Dv, v) * sl;
    }
    if (gg == 0)
      *(float4*)(yp + i0) = make_float4(y[0], y[1], y[2], y[3]);
  }
}

// ---------------- out_proj (64->32) into (b,c,l) = NCHW image --------------
__global__ __launch_bounds__(512) void outproj_k(const float* __restrict__ yt,
    const float* __restrict__ Wout, float* __restrict__ ym)
{
  __shared__ float ys[64][67];
  const int tid = threadIdx.x, lane = tid & 63, ty = tid >> 6;
  const int bi = blockIdx.x >> 6;
  const int l0 = (blockIdx.x & 63) << 6;
  for (int r=ty; r<64; r+=8)
    ys[lane][r] = yt[((size_t)(bi*64+r))*SEQL + l0 + lane];
  __syncthreads();
  float yv[64];
  #pragma unroll
  for (int c=0;c<64;++c) yv[c] = ys[lane][c];
  #pragma unroll
  for (int jj=0;jj<4;++jj){
    int j = ty*4 + jj;
    const float* wr = Wout + j*64;
    float acc = 0.0f;
    #pragma unroll
    for (int c=0;c<64;++c) acc = fmaf(yv[c], wr[c], acc);
    ym[((size_t)(bi*32+j))*SEQL + l0 + lane] = acc;
  }
}

extern "C" void kernel_launch(void* const* d_in, const int* in_sizes, int n_in,
                              void* d_out, int out_size, void* d_ws, size_t ws_size,
                              hipStream_t stream) {
  const float* x        = (const float*)d_in[0];
  const float* conv1_w  = (const float*)d_in[1];
  const float* conv1_b  = (const float*)d_in[2];
  const float* conv2_w  = (const float*)d_in[3];
  const float* conv2_b  = (const float*)d_in[4];
  const float* ln_g     = (const float*)d_in[5];
  const float* ln_b     = (const float*)d_in[6];
  const float* in_proj_w= (const float*)d_in[7];
  const float* conv1d_w = (const float*)d_in[8];
  const float* conv1d_b = (const float*)d_in[9];
  const float* x_proj_w = (const float*)d_in[10];
  const float* dt_proj_w= (const float*)d_in[11];
  const float* dt_proj_b= (const float*)d_in[12];
  const float* A_log    = (const float*)d_in[13];
  const float* Dp       = (const float*)d_in[14];
  const float* out_proj_w=(const float*)d_in[15];
  const float* smooth_w = (const float*)d_in[16];
  const float* smooth_b = (const float*)d_in[17];
  float* out = (float*)d_out;

  float* ws = (float*)d_ws;
  float* t      = ws;                 // (4,64,64,64)  1048576  (free after conv2)
  float* x2     = t      + 1048576;   // (4,32,4096)    524288
  float* xm2    = x2     + 524288;    // (4,64,4096)   1048576
  float* szb    = xm2    + 1048576;   // (4,64,4096)   1048576
  float* dlt    = szb    + 1048576;   // (4,64,4096)   1048576
  float* Bmat   = dlt    + 1048576;   // (4,4096,32)    524288
  float* Cmat   = Bmat   + 524288;    // (4,4096,32)    524288
  float* yt     = Cmat   + 524288;    // (4,64,4096)   1048576
  float* ym     = yt     + 1048576;   // (4,32,4096)    524288
  float* cA     = t;                  // (256,32,64)    524288 (aliases t)
  float* cH     = t + 524288;         // (256,32,64)    524288 (aliases t)

  conv3x3_k<32,64,4,true ,false><<<dim3(16,16,4), 256, 0, stream>>>(x,  conv1_w, conv1_b, nullptr, t);
  conv3x3_k<64,32,4,false,true ><<<dim3(16,8,4), 256, 0, stream>>>(t,  conv2_w, conv2_b, x,       x2);
  mamba_in_k  <<<256, 512, 0, stream>>>(x2, ln_g, ln_b, in_proj_w, conv1d_w, conv1d_b,
                                        x_proj_w, dt_proj_w, dt_proj_b, A_log,
                                        xm2, szb, dlt, Bmat, Cmat, cA, cH);
  scan_p2     <<<512, 256, 0, stream>>>(dlt, xm2, Bmat, Cmat, A_log, Dp, szb, cA, cH, yt);
  outproj_k   <<<256, 512, 0, stream>>>(yt, out_proj_w, ym);
  conv3x3_k<32,32,4,false,false><<<dim3(16,8,4), 256, 0, stream>>>(ym, smooth_w, smooth_b, nullptr, out);
}